// Round 1
// 586.634 us; speedup vs baseline: 1.1528x; 1.1528x over previous
//
#include <hip/hip_runtime.h>

typedef unsigned short u16;
typedef __bf16 bf16x8 __attribute__((ext_vector_type(8)));
typedef float floatx4 __attribute__((ext_vector_type(4)));

#define B_ 2
#define L_ 2048
#define S_ 2048
#define D_ 512
#define H_ 8

static __device__ __forceinline__ u16 f2bf(float f) {
  union { float f; unsigned u; } v; v.f = f;
  unsigned u = v.u;
  return (u16)((u + 0x7FFFu + ((u >> 16) & 1u)) >> 16);  // RNE
}
static __device__ __forceinline__ float bf2f(u16 h) {
  union { unsigned u; float f; } v; v.u = ((unsigned)h) << 16;
  return v.f;
}

// ---------------------------------------------------------------------------
// QKV projection GEMM: C[m][n] = sum_k A[m][k] * W[n][k]   (M=4096,N=512,K=512)
// z: 0 queries->qb (bf16), 1 keys->kb (bf16), 2 values->vb (bf16,+bv)
// ---------------------------------------------------------------------------
__global__ __launch_bounds__(256) void qkv_gemm(
    const float* __restrict__ Qin, const float* __restrict__ Kin, const float* __restrict__ Vin,
    const float* __restrict__ Wq, const float* __restrict__ Wk, const float* __restrict__ Wv,
    const float* __restrict__ bv,
    u16* __restrict__ qo, u16* __restrict__ ko, u16* __restrict__ vo)
{
  __shared__ u16 As[128][72];
  __shared__ u16 Bs[128][72];
  const int z = blockIdx.z;
  const float* A = (z == 0) ? Qin : (z == 1) ? Kin : Vin;
  const float* W = (z == 0) ? Wq : (z == 1) ? Wk : Wv;
  const int tid = threadIdx.x;
  const int m0 = blockIdx.y * 128;
  const int n0 = blockIdx.x * 128;
  const int lane = tid & 63, w = tid >> 6;
  const int ml = lane & 15, kl = lane >> 4;
  const int mqw = (w >> 1) * 64, nq = (w & 1) * 64;
  const int srow = tid >> 4, scg = tid & 15;

  floatx4 acc[4][4] = {};

  for (int k0 = 0; k0 < 512; k0 += 64) {
#pragma unroll
    for (int i = 0; i < 8; ++i) {
      const int r = srow + i * 16;
      float4 av = *(const float4*)&A[(size_t)(m0 + r) * 512 + k0 + scg * 4];
      ushort4 ua; ua.x = f2bf(av.x); ua.y = f2bf(av.y); ua.z = f2bf(av.z); ua.w = f2bf(av.w);
      *(ushort4*)&As[r][scg * 4] = ua;
      float4 wv = *(const float4*)&W[(size_t)(n0 + r) * 512 + k0 + scg * 4];
      ushort4 uw; uw.x = f2bf(wv.x); uw.y = f2bf(wv.y); uw.z = f2bf(wv.z); uw.w = f2bf(wv.w);
      *(ushort4*)&Bs[r][scg * 4] = uw;
    }
    __syncthreads();
#pragma unroll
    for (int kk = 0; kk < 64; kk += 32) {
      bf16x8 af[4], bfv[4];
#pragma unroll
      for (int i = 0; i < 4; ++i) af[i] = *(const bf16x8*)&As[mqw + i * 16 + ml][kk + kl * 8];
#pragma unroll
      for (int j = 0; j < 4; ++j) bfv[j] = *(const bf16x8*)&Bs[nq + j * 16 + ml][kk + kl * 8];
#pragma unroll
      for (int i = 0; i < 4; ++i)
#pragma unroll
        for (int j = 0; j < 4; ++j)
          acc[i][j] = __builtin_amdgcn_mfma_f32_16x16x32_bf16(af[i], bfv[j], acc[i][j], 0, 0, 0);
    }
    __syncthreads();
  }
#pragma unroll
  for (int i = 0; i < 4; ++i)
#pragma unroll
    for (int j = 0; j < 4; ++j) {
      const int gc = n0 + nq + j * 16 + ml;
#pragma unroll
      for (int r = 0; r < 4; ++r) {
        const int gr = m0 + mqw + i * 16 + kl * 4 + r;
        float v = acc[i][j][r];
        if (z == 0)      qo[(size_t)gr * 512 + gc] = f2bf(v);
        else if (z == 1) ko[(size_t)gr * 512 + gc] = f2bf(v);
        else             vo[(size_t)gr * 512 + gc] = f2bf(v + bv[gc]);
      }
    }
}

// ---------------------------------------------------------------------------
// mixed_q: mq[b][h][l][e] = bf16( qb[b][l][e] * mixing[h][e] )
// ---------------------------------------------------------------------------
__global__ __launch_bounds__(256) void mixq_kernel(
    const u16* __restrict__ qb, const float* __restrict__ mixing, u16* __restrict__ mq)
{
  __shared__ float mixs[8 * 512];
  const int tid = threadIdx.x;
#pragma unroll
  for (int i = 0; i < 4; ++i)
    *(float4*)&mixs[(tid + i * 256) * 4] = *(const float4*)&mixing[(tid + i * 256) * 4];
  __syncthreads();
  const size_t unit = (size_t)blockIdx.x * 256 + tid;  // one 8-elem group
  const size_t el = unit * 8;
  const int e = (int)(el & 511);
  const size_t bl = el >> 9;
  const int b = (int)(bl >> 11);
  const int l = (int)(bl & 2047);
  uint4 qv = *(const uint4*)&qb[el];
  const float q0 = bf2f((u16)(qv.x & 0xFFFFu)), q1 = bf2f((u16)(qv.x >> 16));
  const float q2 = bf2f((u16)(qv.y & 0xFFFFu)), q3 = bf2f((u16)(qv.y >> 16));
  const float q4 = bf2f((u16)(qv.z & 0xFFFFu)), q5 = bf2f((u16)(qv.z >> 16));
  const float q6 = bf2f((u16)(qv.w & 0xFFFFu)), q7 = bf2f((u16)(qv.w >> 16));
#pragma unroll
  for (int h = 0; h < 8; ++h) {
    const float* mp = &mixs[h * 512 + e];
    uint4 o;
    o.x = (unsigned)f2bf(q0 * mp[0]) | ((unsigned)f2bf(q1 * mp[1]) << 16);
    o.y = (unsigned)f2bf(q2 * mp[2]) | ((unsigned)f2bf(q3 * mp[3]) << 16);
    o.z = (unsigned)f2bf(q4 * mp[4]) | ((unsigned)f2bf(q5 * mp[5]) << 16);
    o.w = (unsigned)f2bf(q6 * mp[6]) | ((unsigned)f2bf(q7 * mp[7]) << 16);
    *(uint4*)&mq[(((size_t)b * 8 + h) * 2048 + l) * 512 + e] = o;
  }
}

// ---------------------------------------------------------------------------
// Output projection GEMM: out[m][n] = sum_k ctx[m][k]*Wd[n][k] + bd[n]
// ---------------------------------------------------------------------------
__global__ __launch_bounds__(256) void out_gemm(
    const float* __restrict__ A, const float* __restrict__ W,
    const float* __restrict__ bias, float* __restrict__ out)
{
  __shared__ u16 As[128][72];
  __shared__ u16 Bs[128][72];
  const int tid = threadIdx.x;
  const int m0 = blockIdx.y * 128;
  const int n0 = blockIdx.x * 128;
  const int lane = tid & 63, w = tid >> 6;
  const int ml = lane & 15, kl = lane >> 4;
  const int mqw = (w >> 1) * 64, nq = (w & 1) * 64;
  const int srow = tid >> 4, scg = tid & 15;

  floatx4 acc[4][4] = {};

  for (int k0 = 0; k0 < 512; k0 += 64) {
#pragma unroll
    for (int i = 0; i < 8; ++i) {
      const int r = srow + i * 16;
      float4 av = *(const float4*)&A[(size_t)(m0 + r) * 512 + k0 + scg * 4];
      ushort4 ua; ua.x = f2bf(av.x); ua.y = f2bf(av.y); ua.z = f2bf(av.z); ua.w = f2bf(av.w);
      *(ushort4*)&As[r][scg * 4] = ua;
      float4 wv = *(const float4*)&W[(size_t)(n0 + r) * 512 + k0 + scg * 4];
      ushort4 uw; uw.x = f2bf(wv.x); uw.y = f2bf(wv.y); uw.z = f2bf(wv.z); uw.w = f2bf(wv.w);
      *(ushort4*)&Bs[r][scg * 4] = uw;
    }
    __syncthreads();
#pragma unroll
    for (int kk = 0; kk < 64; kk += 32) {
      bf16x8 af[4], bfv[4];
#pragma unroll
      for (int i = 0; i < 4; ++i) af[i] = *(const bf16x8*)&As[mqw + i * 16 + ml][kk + kl * 8];
#pragma unroll
      for (int j = 0; j < 4; ++j) bfv[j] = *(const bf16x8*)&Bs[nq + j * 16 + ml][kk + kl * 8];
#pragma unroll
      for (int i = 0; i < 4; ++i)
#pragma unroll
        for (int j = 0; j < 4; ++j)
          acc[i][j] = __builtin_amdgcn_mfma_f32_16x16x32_bf16(af[i], bfv[j], acc[i][j], 0, 0, 0);
    }
    __syncthreads();
  }
#pragma unroll
  for (int i = 0; i < 4; ++i)
#pragma unroll
    for (int j = 0; j < 4; ++j) {
      const int gc = n0 + nq + j * 16 + ml;
#pragma unroll
      for (int r = 0; r < 4; ++r) {
        const int gr = m0 + mqw + i * 16 + kl * 4 + r;
        out[(size_t)gr * 512 + gc] = acc[i][j][r] + bias[gc];
      }
    }
}

// ---------------------------------------------------------------------------
// Content bias: cb[b][h][s] = sum_d keys[b][s][d] * Wcb[h][d]
// ---------------------------------------------------------------------------
__global__ __launch_bounds__(256) void cb_kernel(
    const float* __restrict__ keys, const float* __restrict__ Wcb, float* __restrict__ cbuf)
{
  __shared__ float Wl[8 * 512];
  const int tid = threadIdx.x;
#pragma unroll
  for (int i = 0; i < 4; ++i) {
    const int idx = tid + i * 256;
    *(float4*)&Wl[idx * 4] = *(const float4*)&Wcb[idx * 4];
  }
  __syncthreads();
  const int w = tid >> 6, lane = tid & 63;
  const int rowid = blockIdx.x * 4 + w;
  const int b = rowid >> 11, s = rowid & 2047;
  const float* kr = keys + (size_t)rowid * 512;
  float acc[8] = {0.f, 0.f, 0.f, 0.f, 0.f, 0.f, 0.f, 0.f};
  for (int e = lane; e < 512; e += 64) {
    const float kv = kr[e];
#pragma unroll
    for (int hh = 0; hh < 8; ++hh) acc[hh] += kv * Wl[hh * 512 + e];
  }
#pragma unroll
  for (int hh = 0; hh < 8; ++hh) {
#pragma unroll
    for (int off = 32; off > 0; off >>= 1) acc[hh] += __shfl_xor(acc[hh], off, 64);
  }
  if (lane == 0) {
#pragma unroll
    for (int hh = 0; hh < 8; ++hh)
      cbuf[((size_t)b * 8 + hh) * 2048 + s] = acc[hh];
  }
}

// ---------------------------------------------------------------------------
// Transpose v: vb [B][S][512] bf16 -> vT [B][512][S] bf16
// ---------------------------------------------------------------------------
__global__ __launch_bounds__(256) void transpose_v(
    const u16* __restrict__ vb, u16* __restrict__ vT)
{
  __shared__ u16 t[64][72];
  const int tid = threadIdx.x;
  const int e0 = blockIdx.x * 64;
  const int s0 = blockIdx.y * 64;
  const int b = blockIdx.z;
  const int rr = tid >> 3, g = tid & 7;
#pragma unroll
  for (int i = 0; i < 2; ++i) {
    const int r = rr + i * 32;
    *(uint4*)&t[r][g * 8] = *(const uint4*)&vb[((size_t)b * S_ + s0 + r) * 512 + e0 + g * 8];
  }
  __syncthreads();
#pragma unroll
  for (int i = 0; i < 2; ++i) {
    const int er = rr + i * 32;
    uint4 o;
    o.x = (unsigned)t[g * 8 + 0][er] | ((unsigned)t[g * 8 + 1][er] << 16);
    o.y = (unsigned)t[g * 8 + 2][er] | ((unsigned)t[g * 8 + 3][er] << 16);
    o.z = (unsigned)t[g * 8 + 4][er] | ((unsigned)t[g * 8 + 5][er] << 16);
    o.w = (unsigned)t[g * 8 + 6][er] | ((unsigned)t[g * 8 + 7][er] << 16);
    *(uint4*)&vT[((size_t)b * 512 + e0 + er) * S_ + s0 + g * 8] = o;
  }
}

// ---------------------------------------------------------------------------
// Scores GEMM (per b,h): sc[l][s] = (sum_e mq[bh][l][e]*k[s][e] + cb[s]) / 8
// BF16OUT=1: write bf16 scores to sb (half the write traffic; softmax reads
// bf16 — numerically identical to the old path which rounded to bf16 anyway).
// BF16OUT=0: write fp32 scores into the probs output region (in-place path).
// ---------------------------------------------------------------------------
template<int BF16OUT>
__global__ __launch_bounds__(256) void scores_gemm(
    const u16* __restrict__ mq, const u16* __restrict__ kb,
    const float* __restrict__ cbuf, float* __restrict__ sc, u16* __restrict__ sb)
{
  __shared__ u16 As[128][72];
  __shared__ u16 Bs[128][72];
  const int tid = threadIdx.x;
  const int bh = blockIdx.z, b = bh >> 3;
  const int m0 = blockIdx.y * 128;
  const int n0 = blockIdx.x * 128;
  const u16* mqb = mq + (size_t)bh * L_ * 512;
  const u16* kbb = kb + (size_t)b * S_ * 512;
  const int lane = tid & 63, w = tid >> 6;
  const int ml = lane & 15, kl = lane >> 4;
  const int mqw = (w >> 1) * 64, nq = (w & 1) * 64;
  const int brow = tid >> 3, bcg = tid & 7;

  floatx4 acc[4][4] = {};

  for (int k0 = 0; k0 < 512; k0 += 64) {
#pragma unroll
    for (int i = 0; i < 4; ++i) {
      const int r = brow + i * 32;
      *(uint4*)&As[r][bcg * 8] = *(const uint4*)&mqb[(size_t)(m0 + r) * 512 + k0 + bcg * 8];
      *(uint4*)&Bs[r][bcg * 8] = *(const uint4*)&kbb[(size_t)(n0 + r) * 512 + k0 + bcg * 8];
    }
    __syncthreads();
#pragma unroll
    for (int kk = 0; kk < 64; kk += 32) {
      bf16x8 af[4], bfv[4];
#pragma unroll
      for (int i = 0; i < 4; ++i) af[i] = *(const bf16x8*)&As[mqw + i * 16 + ml][kk + kl * 8];
#pragma unroll
      for (int j = 0; j < 4; ++j) bfv[j] = *(const bf16x8*)&Bs[nq + j * 16 + ml][kk + kl * 8];
#pragma unroll
      for (int i = 0; i < 4; ++i)
#pragma unroll
        for (int j = 0; j < 4; ++j)
          acc[i][j] = __builtin_amdgcn_mfma_f32_16x16x32_bf16(af[i], bfv[j], acc[i][j], 0, 0, 0);
    }
    __syncthreads();
  }
  if constexpr (BF16OUT) {
    u16* outp = sb + ((size_t)bh * L_ + m0) * S_ + n0;
#pragma unroll
    for (int j = 0; j < 4; ++j) {
      const int gcl = nq + j * 16 + ml;
      const float cbv = cbuf[(size_t)bh * S_ + n0 + gcl];
#pragma unroll
      for (int i = 0; i < 4; ++i)
#pragma unroll
        for (int r = 0; r < 4; ++r) {
          const int grl = mqw + i * 16 + kl * 4 + r;
          outp[(size_t)grl * S_ + gcl] = f2bf((acc[i][j][r] + cbv) * 0.125f);
        }
    }
  } else {
    float* outp = sc + ((size_t)bh * L_ + m0) * S_ + n0;
#pragma unroll
    for (int j = 0; j < 4; ++j) {
      const int gcl = nq + j * 16 + ml;
      const float cbv = cbuf[(size_t)bh * S_ + n0 + gcl];
#pragma unroll
      for (int i = 0; i < 4; ++i)
#pragma unroll
        for (int r = 0; r < 4; ++r) {
          const int grl = mqw + i * 16 + kl * 4 + r;
          outp[(size_t)grl * S_ + gcl] = (acc[i][j][r] + cbv) * 0.125f;
        }
    }
  }
}

// ---------------------------------------------------------------------------
// Streaming softmax: one wave per row. 32 values/lane held in VGPRs, single
// pass: max-reduce (6 shfl), exp in-register, sum-reduce (6 shfl), scaled
// fp32 store to the probs output. Pure BW kernel at ~full occupancy.
// BF16IN=1: read bf16 scores from sb. BF16IN=0: read/write fp32 in place.
// ---------------------------------------------------------------------------
template<int BF16IN>
__global__ __launch_bounds__(256) void softmax_stream(
    const u16* __restrict__ sb, float* probs)
{
  const int tid = threadIdx.x;
  const int row = blockIdx.x * 4 + (tid >> 6);   // bh*2048 + l
  const int lane = tid & 63;
  float s[32];
  if constexpr (BF16IN) {
    const u16* rp = sb + (size_t)row * 2048;
#pragma unroll
    for (int j = 0; j < 8; ++j) {
      uint2 v = *(const uint2*)&rp[lane * 4 + j * 256];
      s[4 * j + 0] = bf2f((u16)(v.x & 0xFFFFu));
      s[4 * j + 1] = bf2f((u16)(v.x >> 16));
      s[4 * j + 2] = bf2f((u16)(v.y & 0xFFFFu));
      s[4 * j + 3] = bf2f((u16)(v.y >> 16));
    }
  } else {
    const float* rp = probs + (size_t)row * 2048;
#pragma unroll
    for (int j = 0; j < 8; ++j) {
      float4 v = *(const float4*)&rp[lane * 4 + j * 256];
      s[4 * j + 0] = v.x; s[4 * j + 1] = v.y; s[4 * j + 2] = v.z; s[4 * j + 3] = v.w;
    }
  }
  float m = -3.0e38f;
#pragma unroll
  for (int i = 0; i < 32; ++i) m = fmaxf(m, s[i]);
#pragma unroll
  for (int off = 32; off > 0; off >>= 1) m = fmaxf(m, __shfl_xor(m, off, 64));
  float s0 = 0.f, s1 = 0.f, s2 = 0.f, s3 = 0.f;
#pragma unroll
  for (int i = 0; i < 32; i += 4) {
    s[i + 0] = __expf(s[i + 0] - m); s0 += s[i + 0];
    s[i + 1] = __expf(s[i + 1] - m); s1 += s[i + 1];
    s[i + 2] = __expf(s[i + 2] - m); s2 += s[i + 2];
    s[i + 3] = __expf(s[i + 3] - m); s3 += s[i + 3];
  }
  float sum = (s0 + s1) + (s2 + s3);
#pragma unroll
  for (int off = 32; off > 0; off >>= 1) sum += __shfl_xor(sum, off, 64);
  const float rl = 1.0f / sum;
  float* op = probs + (size_t)row * 2048;
#pragma unroll
  for (int j = 0; j < 8; ++j) {
    float4 o;
    o.x = s[4 * j + 0] * rl; o.y = s[4 * j + 1] * rl;
    o.z = s[4 * j + 2] * rl; o.w = s[4 * j + 3] * rl;
    *(float4*)&op[lane * 4 + j * 256] = o;
  }
}

// ---------------------------------------------------------------------------
// ctx GEMM (per b,h): ctx[l][dv] = sum_s p[l][s] * vT[dv][s]
// M=2048, N=64, K=2048. BM=64, BN=64, split-K=2 -> 1024 blocks (50% occ).
// A staged from fp32 probs with bf16 convert; B staged from vT (pure copy).
// Split-K partials combined with fp32 atomicAdd into pre-zeroed ctx.
// ---------------------------------------------------------------------------
__global__ __launch_bounds__(256) void ctx_gemm(
    const float* __restrict__ probs, const u16* __restrict__ vT, float* __restrict__ ctx)
{
  __shared__ u16 As[64][72];
  __shared__ u16 Bs[64][72];
  const int tid = threadIdx.x;
  const int bh = blockIdx.z, b = bh >> 3, h = bh & 7;
  const int m0 = blockIdx.x * 64;   // l tile
  const int kz = blockIdx.y;        // K split half
  const float* Ap = probs + ((size_t)bh * L_ + m0) * S_;
  const u16* Bp = vT + ((size_t)b * 512 + h * 64) * S_;
  const int lane = tid & 63, w = tid >> 6;
  const int ml = lane & 15, kl = lane >> 4;
  const int srow = tid >> 4, scg = tid & 15;   // A staging: 16 rows x (16 groups of 4)
  const int brow = tid >> 3, bcg = tid & 7;    // B staging: 32 rows x (8 groups of 8)

  floatx4 acc[4] = {};

  const int kend = kz * 1024 + 1024;
  for (int k0 = kz * 1024; k0 < kend; k0 += 64) {
#pragma unroll
    for (int i = 0; i < 4; ++i) {
      const int r = srow + i * 16;
      float4 av = *(const float4*)&Ap[(size_t)r * S_ + k0 + scg * 4];
      ushort4 ua; ua.x = f2bf(av.x); ua.y = f2bf(av.y); ua.z = f2bf(av.z); ua.w = f2bf(av.w);
      *(ushort4*)&As[r][scg * 4] = ua;
    }
#pragma unroll
    for (int i = 0; i < 2; ++i) {
      const int r = brow + i * 32;
      *(uint4*)&Bs[r][bcg * 8] = *(const uint4*)&Bp[(size_t)r * S_ + k0 + bcg * 8];
    }
    __syncthreads();
#pragma unroll
    for (int kk = 0; kk < 64; kk += 32) {
      bf16x8 af = *(const bf16x8*)&As[w * 16 + ml][kk + kl * 8];
#pragma unroll
      for (int j = 0; j < 4; ++j) {
        bf16x8 bfv = *(const bf16x8*)&Bs[j * 16 + ml][kk + kl * 8];
        acc[j] = __builtin_amdgcn_mfma_f32_16x16x32_bf16(af, bfv, acc[j], 0, 0, 0);
      }
    }
    __syncthreads();
  }
#pragma unroll
  for (int j = 0; j < 4; ++j) {
    const int gc = h * 64 + j * 16 + ml;
#pragma unroll
    for (int r = 0; r < 4; ++r) {
      const int gl = m0 + w * 16 + kl * 4 + r;
      atomicAdd(&ctx[((size_t)b * L_ + gl) * 512 + gc], acc[j][r]);
    }
  }
}

// ---------------------------------------------------------------------------
// Zero the ctx accumulator (split-K target). 2M floats, float4 stores.
// ---------------------------------------------------------------------------
__global__ __launch_bounds__(256) void zero_ctx(float* __restrict__ p)
{
  const size_t i = ((size_t)blockIdx.x * 256 + threadIdx.x) * 4;
  float4 z; z.x = 0.f; z.y = 0.f; z.z = 0.f; z.w = 0.f;
  *(float4*)&p[i] = z;
}

// ---------------------------------------------------------------------------
extern "C" void kernel_launch(void* const* d_in, const int* in_sizes, int n_in,
                              void* d_out, int out_size, void* d_ws, size_t ws_size,
                              hipStream_t stream) {
  const float* queries = (const float*)d_in[0];
  const float* keys    = (const float*)d_in[1];
  const float* values  = (const float*)d_in[2];
  const float* Wq  = (const float*)d_in[4];
  const float* Wk  = (const float*)d_in[5];
  const float* Wv  = (const float*)d_in[6];
  const float* bv  = (const float*)d_in[7];
  const float* Wcb = (const float*)d_in[8];
  const float* mixing = (const float*)d_in[9];
  const float* Wd  = (const float*)d_in[10];
  const float* bd  = (const float*)d_in[11];

  float* out   = (float*)d_out;                         // [B,L,512] fp32
  float* probs = out + (size_t)B_ * L_ * 512;           // [B,H,L,S] fp32

  char* ws = (char*)d_ws;
  u16*   qb  = (u16*)(ws);                              //  4 MB  bf16 [B*L,512]
  u16*   kb  = (u16*)(ws + (size_t)4  * 1024 * 1024);   //  4 MB  bf16 [B*S,512]
  u16*   vb  = (u16*)(ws + (size_t)8  * 1024 * 1024);   //  4 MB  bf16 [B*S,512]
  u16*   vT  = (u16*)(ws + (size_t)12 * 1024 * 1024);   //  4 MB  bf16 [B,512,S]
  float* cbuf= (float*)(ws + (size_t)16 * 1024 * 1024); // 128 KB fp32 [B,H,S]
  float* ctx = (float*)(ws + (size_t)17 * 1024 * 1024); //  8 MB  fp32 [B*L,512]
  u16*   mq  = (u16*)(ws + (size_t)25 * 1024 * 1024);   // 32 MB  bf16 [B,H,L,512]
  // optional bf16 scores buffer (128 MiB) after mq, if the workspace allows
  const size_t SB16_OFF = (size_t)57 * 1024 * 1024;
  const size_t SB16_SZ  = (size_t)B_ * H_ * L_ * S_ * 2;
  u16* sb16 = (u16*)(ws + SB16_OFF);
  const bool bigws = (ws_size >= SB16_OFF + SB16_SZ);

  hipLaunchKernelGGL(qkv_gemm, dim3(4, 32, 3), dim3(256), 0, stream,
                     queries, keys, values, Wq, Wk, Wv, bv, qb, kb, vb);
  hipLaunchKernelGGL(mixq_kernel, dim3(1024), dim3(256), 0, stream, qb, mixing, mq);
  hipLaunchKernelGGL(cb_kernel, dim3(1024), dim3(256), 0, stream, keys, Wcb, cbuf);
  hipLaunchKernelGGL(transpose_v, dim3(8, 32, 2), dim3(256), 0, stream, vb, vT);
  hipLaunchKernelGGL(zero_ctx, dim3(2048), dim3(256), 0, stream, ctx);
  if (bigws) {
    hipLaunchKernelGGL(HIP_KERNEL_NAME(scores_gemm<1>), dim3(16, 16, 16), dim3(256), 0, stream,
                       mq, kb, cbuf, probs, sb16);
    hipLaunchKernelGGL(HIP_KERNEL_NAME(softmax_stream<1>), dim3(8192), dim3(256), 0, stream,
                       sb16, probs);
  } else {
    hipLaunchKernelGGL(HIP_KERNEL_NAME(scores_gemm<0>), dim3(16, 16, 16), dim3(256), 0, stream,
                       mq, kb, cbuf, probs, sb16);
    hipLaunchKernelGGL(HIP_KERNEL_NAME(softmax_stream<0>), dim3(8192), dim3(256), 0, stream,
                       sb16, probs);
  }
  hipLaunchKernelGGL(ctx_gemm, dim3(32, 2, 16), dim3(256), 0, stream, probs, vT, ctx);
  hipLaunchKernelGGL(out_gemm, dim3(4, 32, 1), dim3(256), 0, stream,
                     ctx, Wd, bd, out);
}

// Round 2
// 579.604 us; speedup vs baseline: 1.1668x; 1.0121x over previous
//
#include <hip/hip_runtime.h>

typedef unsigned short u16;
typedef __bf16 bf16x8 __attribute__((ext_vector_type(8)));
typedef float floatx4 __attribute__((ext_vector_type(4)));

#define B_ 2
#define L_ 2048
#define S_ 2048
#define D_ 512
#define H_ 8

static __device__ __forceinline__ u16 f2bf(float f) {
  union { float f; unsigned u; } v; v.f = f;
  unsigned u = v.u;
  return (u16)((u + 0x7FFFu + ((u >> 16) & 1u)) >> 16);  // RNE
}
static __device__ __forceinline__ float bf2f(u16 h) {
  union { unsigned u; float f; } v; v.u = ((unsigned)h) << 16;
  return v.f;
}

// async global->LDS, 16B per lane. LDS dest is wave-uniform base + lane*16.
static __device__ __forceinline__ void gload16(const void* g, void* l) {
  __builtin_amdgcn_global_load_lds(
      (const __attribute__((address_space(1))) void*)g,
      (__attribute__((address_space(3))) void*)l, 16, 0, 0);
}

// ---------------------------------------------------------------------------
// QKV projection GEMM: C[m][n] = sum_k A[m][k] * W[n][k]   (M=4096,N=512,K=512)
// z: 0 queries->qb (bf16), 1 keys->kb (bf16), 2 values->vb (bf16,+bv)
// ---------------------------------------------------------------------------
__global__ __launch_bounds__(256) void qkv_gemm(
    const float* __restrict__ Qin, const float* __restrict__ Kin, const float* __restrict__ Vin,
    const float* __restrict__ Wq, const float* __restrict__ Wk, const float* __restrict__ Wv,
    const float* __restrict__ bv,
    u16* __restrict__ qo, u16* __restrict__ ko, u16* __restrict__ vo)
{
  __shared__ u16 As[128][72];
  __shared__ u16 Bs[128][72];
  const int z = blockIdx.z;
  const float* A = (z == 0) ? Qin : (z == 1) ? Kin : Vin;
  const float* W = (z == 0) ? Wq : (z == 1) ? Wk : Wv;
  const int tid = threadIdx.x;
  const int m0 = blockIdx.y * 128;
  const int n0 = blockIdx.x * 128;
  const int lane = tid & 63, w = tid >> 6;
  const int ml = lane & 15, kl = lane >> 4;
  const int mqw = (w >> 1) * 64, nq = (w & 1) * 64;
  const int srow = tid >> 4, scg = tid & 15;

  floatx4 acc[4][4] = {};

  for (int k0 = 0; k0 < 512; k0 += 64) {
#pragma unroll
    for (int i = 0; i < 8; ++i) {
      const int r = srow + i * 16;
      float4 av = *(const float4*)&A[(size_t)(m0 + r) * 512 + k0 + scg * 4];
      ushort4 ua; ua.x = f2bf(av.x); ua.y = f2bf(av.y); ua.z = f2bf(av.z); ua.w = f2bf(av.w);
      *(ushort4*)&As[r][scg * 4] = ua;
      float4 wv = *(const float4*)&W[(size_t)(n0 + r) * 512 + k0 + scg * 4];
      ushort4 uw; uw.x = f2bf(wv.x); uw.y = f2bf(wv.y); uw.z = f2bf(wv.z); uw.w = f2bf(wv.w);
      *(ushort4*)&Bs[r][scg * 4] = uw;
    }
    __syncthreads();
#pragma unroll
    for (int kk = 0; kk < 64; kk += 32) {
      bf16x8 af[4], bfv[4];
#pragma unroll
      for (int i = 0; i < 4; ++i) af[i] = *(const bf16x8*)&As[mqw + i * 16 + ml][kk + kl * 8];
#pragma unroll
      for (int j = 0; j < 4; ++j) bfv[j] = *(const bf16x8*)&Bs[nq + j * 16 + ml][kk + kl * 8];
#pragma unroll
      for (int i = 0; i < 4; ++i)
#pragma unroll
        for (int j = 0; j < 4; ++j)
          acc[i][j] = __builtin_amdgcn_mfma_f32_16x16x32_bf16(af[i], bfv[j], acc[i][j], 0, 0, 0);
    }
    __syncthreads();
  }
#pragma unroll
  for (int i = 0; i < 4; ++i)
#pragma unroll
    for (int j = 0; j < 4; ++j) {
      const int gc = n0 + nq + j * 16 + ml;
#pragma unroll
      for (int r = 0; r < 4; ++r) {
        const int gr = m0 + mqw + i * 16 + kl * 4 + r;
        float v = acc[i][j][r];
        if (z == 0)      qo[(size_t)gr * 512 + gc] = f2bf(v);
        else if (z == 1) ko[(size_t)gr * 512 + gc] = f2bf(v);
        else             vo[(size_t)gr * 512 + gc] = f2bf(v + bv[gc]);
      }
    }
}

// ---------------------------------------------------------------------------
// mixed_q: mq[b][h][l][e] = bf16( qb[b][l][e] * mixing[h][e] )
// ---------------------------------------------------------------------------
__global__ __launch_bounds__(256) void mixq_kernel(
    const u16* __restrict__ qb, const float* __restrict__ mixing, u16* __restrict__ mq)
{
  __shared__ float mixs[8 * 512];
  const int tid = threadIdx.x;
#pragma unroll
  for (int i = 0; i < 4; ++i)
    *(float4*)&mixs[(tid + i * 256) * 4] = *(const float4*)&mixing[(tid + i * 256) * 4];
  __syncthreads();
  const size_t unit = (size_t)blockIdx.x * 256 + tid;  // one 8-elem group
  const size_t el = unit * 8;
  const int e = (int)(el & 511);
  const size_t bl = el >> 9;
  const int b = (int)(bl >> 11);
  const int l = (int)(bl & 2047);
  uint4 qv = *(const uint4*)&qb[el];
  const float q0 = bf2f((u16)(qv.x & 0xFFFFu)), q1 = bf2f((u16)(qv.x >> 16));
  const float q2 = bf2f((u16)(qv.y & 0xFFFFu)), q3 = bf2f((u16)(qv.y >> 16));
  const float q4 = bf2f((u16)(qv.z & 0xFFFFu)), q5 = bf2f((u16)(qv.z >> 16));
  const float q6 = bf2f((u16)(qv.w & 0xFFFFu)), q7 = bf2f((u16)(qv.w >> 16));
#pragma unroll
  for (int h = 0; h < 8; ++h) {
    const float* mp = &mixs[h * 512 + e];
    uint4 o;
    o.x = (unsigned)f2bf(q0 * mp[0]) | ((unsigned)f2bf(q1 * mp[1]) << 16);
    o.y = (unsigned)f2bf(q2 * mp[2]) | ((unsigned)f2bf(q3 * mp[3]) << 16);
    o.z = (unsigned)f2bf(q4 * mp[4]) | ((unsigned)f2bf(q5 * mp[5]) << 16);
    o.w = (unsigned)f2bf(q6 * mp[6]) | ((unsigned)f2bf(q7 * mp[7]) << 16);
    *(uint4*)&mq[(((size_t)b * 8 + h) * 2048 + l) * 512 + e] = o;
  }
}

// ---------------------------------------------------------------------------
// Output projection GEMM: out[m][n] = sum_k ctx[m][k]*Wd[n][k] + bd[n]
// ---------------------------------------------------------------------------
__global__ __launch_bounds__(256) void out_gemm(
    const float* __restrict__ A, const float* __restrict__ W,
    const float* __restrict__ bias, float* __restrict__ out)
{
  __shared__ u16 As[128][72];
  __shared__ u16 Bs[128][72];
  const int tid = threadIdx.x;
  const int m0 = blockIdx.y * 128;
  const int n0 = blockIdx.x * 128;
  const int lane = tid & 63, w = tid >> 6;
  const int ml = lane & 15, kl = lane >> 4;
  const int mqw = (w >> 1) * 64, nq = (w & 1) * 64;
  const int srow = tid >> 4, scg = tid & 15;

  floatx4 acc[4][4] = {};

  for (int k0 = 0; k0 < 512; k0 += 64) {
#pragma unroll
    for (int i = 0; i < 8; ++i) {
      const int r = srow + i * 16;
      float4 av = *(const float4*)&A[(size_t)(m0 + r) * 512 + k0 + scg * 4];
      ushort4 ua; ua.x = f2bf(av.x); ua.y = f2bf(av.y); ua.z = f2bf(av.z); ua.w = f2bf(av.w);
      *(ushort4*)&As[r][scg * 4] = ua;
      float4 wv = *(const float4*)&W[(size_t)(n0 + r) * 512 + k0 + scg * 4];
      ushort4 uw; uw.x = f2bf(wv.x); uw.y = f2bf(wv.y); uw.z = f2bf(wv.z); uw.w = f2bf(wv.w);
      *(ushort4*)&Bs[r][scg * 4] = uw;
    }
    __syncthreads();
#pragma unroll
    for (int kk = 0; kk < 64; kk += 32) {
      bf16x8 af[4], bfv[4];
#pragma unroll
      for (int i = 0; i < 4; ++i) af[i] = *(const bf16x8*)&As[mqw + i * 16 + ml][kk + kl * 8];
#pragma unroll
      for (int j = 0; j < 4; ++j) bfv[j] = *(const bf16x8*)&Bs[nq + j * 16 + ml][kk + kl * 8];
#pragma unroll
      for (int i = 0; i < 4; ++i)
#pragma unroll
        for (int j = 0; j < 4; ++j)
          acc[i][j] = __builtin_amdgcn_mfma_f32_16x16x32_bf16(af[i], bfv[j], acc[i][j], 0, 0, 0);
    }
    __syncthreads();
  }
#pragma unroll
  for (int i = 0; i < 4; ++i)
#pragma unroll
    for (int j = 0; j < 4; ++j) {
      const int gc = n0 + nq + j * 16 + ml;
#pragma unroll
      for (int r = 0; r < 4; ++r) {
        const int gr = m0 + mqw + i * 16 + kl * 4 + r;
        out[(size_t)gr * 512 + gc] = acc[i][j][r] + bias[gc];
      }
    }
}

// ---------------------------------------------------------------------------
// Content bias: cb[b][h][s] = sum_d keys[b][s][d] * Wcb[h][d]
// ---------------------------------------------------------------------------
__global__ __launch_bounds__(256) void cb_kernel(
    const float* __restrict__ keys, const float* __restrict__ Wcb, float* __restrict__ cbuf)
{
  __shared__ float Wl[8 * 512];
  const int tid = threadIdx.x;
#pragma unroll
  for (int i = 0; i < 4; ++i) {
    const int idx = tid + i * 256;
    *(float4*)&Wl[idx * 4] = *(const float4*)&Wcb[idx * 4];
  }
  __syncthreads();
  const int w = tid >> 6, lane = tid & 63;
  const int rowid = blockIdx.x * 4 + w;
  const int b = rowid >> 11, s = rowid & 2047;
  const float* kr = keys + (size_t)rowid * 512;
  float acc[8] = {0.f, 0.f, 0.f, 0.f, 0.f, 0.f, 0.f, 0.f};
  for (int e = lane; e < 512; e += 64) {
    const float kv = kr[e];
#pragma unroll
    for (int hh = 0; hh < 8; ++hh) acc[hh] += kv * Wl[hh * 512 + e];
  }
#pragma unroll
  for (int hh = 0; hh < 8; ++hh) {
#pragma unroll
    for (int off = 32; off > 0; off >>= 1) acc[hh] += __shfl_xor(acc[hh], off, 64);
  }
  if (lane == 0) {
#pragma unroll
    for (int hh = 0; hh < 8; ++hh)
      cbuf[((size_t)b * 8 + hh) * 2048 + s] = acc[hh];
  }
}

// ---------------------------------------------------------------------------
// Transpose v: vb [B][S][512] bf16 -> vT [B][512][S] bf16
// ---------------------------------------------------------------------------
__global__ __launch_bounds__(256) void transpose_v(
    const u16* __restrict__ vb, u16* __restrict__ vT)
{
  __shared__ u16 t[64][72];
  const int tid = threadIdx.x;
  const int e0 = blockIdx.x * 64;
  const int s0 = blockIdx.y * 64;
  const int b = blockIdx.z;
  const int rr = tid >> 3, g = tid & 7;
#pragma unroll
  for (int i = 0; i < 2; ++i) {
    const int r = rr + i * 32;
    *(uint4*)&t[r][g * 8] = *(const uint4*)&vb[((size_t)b * S_ + s0 + r) * 512 + e0 + g * 8];
  }
  __syncthreads();
#pragma unroll
  for (int i = 0; i < 2; ++i) {
    const int er = rr + i * 32;
    uint4 o;
    o.x = (unsigned)t[g * 8 + 0][er] | ((unsigned)t[g * 8 + 1][er] << 16);
    o.y = (unsigned)t[g * 8 + 2][er] | ((unsigned)t[g * 8 + 3][er] << 16);
    o.z = (unsigned)t[g * 8 + 4][er] | ((unsigned)t[g * 8 + 5][er] << 16);
    o.w = (unsigned)t[g * 8 + 6][er] | ((unsigned)t[g * 8 + 7][er] << 16);
    *(uint4*)&vT[((size_t)b * 512 + e0 + er) * S_ + s0 + g * 8] = o;
  }
}

// ---------------------------------------------------------------------------
// Scores GEMM (per b,h): sc[l][s] = (sum_e mq[bh][l][e]*k[s][e] + cb[s]) / 8
// Staging via global_load_lds width-16 into LINEAR (unpadded) LDS — both
// operands are already bf16, so staging is a pure async DMA (m97 structure).
// BF16OUT=1: bf16 scores to sb. BF16OUT=0: fp32 scores into probs region.
// ---------------------------------------------------------------------------
template<int BF16OUT>
__global__ __launch_bounds__(256) void scores_gemm(
    const u16* __restrict__ mq, const u16* __restrict__ kb,
    const float* __restrict__ cbuf, float* __restrict__ sc, u16* __restrict__ sb)
{
  __shared__ u16 As[128][64];   // linear: row stride 128B (global_load_lds dest)
  __shared__ u16 Bs[128][64];
  const int tid = threadIdx.x;
  const int bh = blockIdx.z, b = bh >> 3;
  const int m0 = blockIdx.y * 128;
  const int n0 = blockIdx.x * 128;
  const u16* mqb = mq + (size_t)bh * L_ * 512;
  const u16* kbb = kb + (size_t)b * S_ * 512;
  const int lane = tid & 63, w = tid >> 6;
  const int ml = lane & 15, kl = lane >> 4;
  const int mqw = (w >> 1) * 64, nq = (w & 1) * 64;
  const int lr = lane >> 3;          // sub-row within 8-row chunk
  const int lc = (lane & 7) * 8;     // u16 col within 64

  floatx4 acc[4][4] = {};

  for (int k0 = 0; k0 < 512; k0 += 64) {
#pragma unroll
    for (int i = 0; i < 4; ++i) {
      const int c = w * 4 + i;       // 1KB chunk = 8 rows of 128B
      const int r = c * 8 + lr;
      gload16(&mqb[(size_t)(m0 + r) * 512 + k0 + lc], &As[c * 8][0]);
      gload16(&kbb[(size_t)(n0 + r) * 512 + k0 + lc], &Bs[c * 8][0]);
    }
    __syncthreads();
#pragma unroll
    for (int kk = 0; kk < 64; kk += 32) {
      bf16x8 af[4], bfv[4];
#pragma unroll
      for (int i = 0; i < 4; ++i) af[i] = *(const bf16x8*)&As[mqw + i * 16 + ml][kk + kl * 8];
#pragma unroll
      for (int j = 0; j < 4; ++j) bfv[j] = *(const bf16x8*)&Bs[nq + j * 16 + ml][kk + kl * 8];
#pragma unroll
      for (int i = 0; i < 4; ++i)
#pragma unroll
        for (int j = 0; j < 4; ++j)
          acc[i][j] = __builtin_amdgcn_mfma_f32_16x16x32_bf16(af[i], bfv[j], acc[i][j], 0, 0, 0);
    }
    __syncthreads();
  }
  if constexpr (BF16OUT) {
    u16* outp = sb + ((size_t)bh * L_ + m0) * S_ + n0;
#pragma unroll
    for (int j = 0; j < 4; ++j) {
      const int gcl = nq + j * 16 + ml;
      const float cbv = cbuf[(size_t)bh * S_ + n0 + gcl];
#pragma unroll
      for (int i = 0; i < 4; ++i)
#pragma unroll
        for (int r = 0; r < 4; ++r) {
          const int grl = mqw + i * 16 + kl * 4 + r;
          outp[(size_t)grl * S_ + gcl] = f2bf((acc[i][j][r] + cbv) * 0.125f);
        }
    }
  } else {
    float* outp = sc + ((size_t)bh * L_ + m0) * S_ + n0;
#pragma unroll
    for (int j = 0; j < 4; ++j) {
      const int gcl = nq + j * 16 + ml;
      const float cbv = cbuf[(size_t)bh * S_ + n0 + gcl];
#pragma unroll
      for (int i = 0; i < 4; ++i)
#pragma unroll
        for (int r = 0; r < 4; ++r) {
          const int grl = mqw + i * 16 + kl * 4 + r;
          outp[(size_t)grl * S_ + gcl] = (acc[i][j][r] + cbv) * 0.125f;
        }
    }
  }
}

// ---------------------------------------------------------------------------
// Streaming softmax: one wave per row, 32 vals/lane in VGPRs, single pass.
// BF16IN=1: read bf16 scores from sb, write fp32 probs AND a bf16 probs copy
// in-place into sb (consumed by ctx_gemm; saves the fp32 probs re-read).
// BF16IN=0: fp32 in place, no bf16 copy.
// ---------------------------------------------------------------------------
template<int BF16IN>
__global__ __launch_bounds__(256) void softmax_stream(
    u16* __restrict__ sb, float* probs)
{
  const int tid = threadIdx.x;
  const int row = blockIdx.x * 4 + (tid >> 6);   // bh*2048 + l
  const int lane = tid & 63;
  float s[32];
  if constexpr (BF16IN) {
    const u16* rp = sb + (size_t)row * 2048;
#pragma unroll
    for (int j = 0; j < 8; ++j) {
      uint2 v = *(const uint2*)&rp[lane * 4 + j * 256];
      s[4 * j + 0] = bf2f((u16)(v.x & 0xFFFFu));
      s[4 * j + 1] = bf2f((u16)(v.x >> 16));
      s[4 * j + 2] = bf2f((u16)(v.y & 0xFFFFu));
      s[4 * j + 3] = bf2f((u16)(v.y >> 16));
    }
  } else {
    const float* rp = probs + (size_t)row * 2048;
#pragma unroll
    for (int j = 0; j < 8; ++j) {
      float4 v = *(const float4*)&rp[lane * 4 + j * 256];
      s[4 * j + 0] = v.x; s[4 * j + 1] = v.y; s[4 * j + 2] = v.z; s[4 * j + 3] = v.w;
    }
  }
  float m = -3.0e38f;
#pragma unroll
  for (int i = 0; i < 32; ++i) m = fmaxf(m, s[i]);
#pragma unroll
  for (int off = 32; off > 0; off >>= 1) m = fmaxf(m, __shfl_xor(m, off, 64));
  float s0 = 0.f, s1 = 0.f, s2 = 0.f, s3 = 0.f;
#pragma unroll
  for (int i = 0; i < 32; i += 4) {
    s[i + 0] = __expf(s[i + 0] - m); s0 += s[i + 0];
    s[i + 1] = __expf(s[i + 1] - m); s1 += s[i + 1];
    s[i + 2] = __expf(s[i + 2] - m); s2 += s[i + 2];
    s[i + 3] = __expf(s[i + 3] - m); s3 += s[i + 3];
  }
  float sum = (s0 + s1) + (s2 + s3);
#pragma unroll
  for (int off = 32; off > 0; off >>= 1) sum += __shfl_xor(sum, off, 64);
  const float rl = 1.0f / sum;
  float* op = probs + (size_t)row * 2048;
  u16* bp = sb + (size_t)row * 2048;
#pragma unroll
  for (int j = 0; j < 8; ++j) {
    float4 o;
    o.x = s[4 * j + 0] * rl; o.y = s[4 * j + 1] * rl;
    o.z = s[4 * j + 2] * rl; o.w = s[4 * j + 3] * rl;
    *(float4*)&op[lane * 4 + j * 256] = o;
    if constexpr (BF16IN) {
      uint2 t;
      t.x = (unsigned)f2bf(o.x) | ((unsigned)f2bf(o.y) << 16);
      t.y = (unsigned)f2bf(o.z) | ((unsigned)f2bf(o.w) << 16);
      *(uint2*)&bp[lane * 4 + j * 256] = t;
    }
  }
}

// ---------------------------------------------------------------------------
// ctx GEMM (per b,h): ctx[l][dv] = sum_s p[l][s] * vT[dv][s]
// M=2048, N=64, K=2048. BM=64, BN=64, full-K loop, direct fp32 stores
// (no split-K / atomics / zero pass). BF16IN=1: A read from bf16 probs copy
// via global_load_lds (pure DMA staging). BF16IN=0: A reg-staged from fp32.
// ---------------------------------------------------------------------------
template<int BF16IN>
__global__ __launch_bounds__(256) void ctx_gemm(
    const float* __restrict__ probsf, const u16* __restrict__ pb,
    const u16* __restrict__ vT, float* __restrict__ ctx)
{
  __shared__ u16 As[64][64];   // linear, 8KB
  __shared__ u16 Bs[64][64];
  const int tid = threadIdx.x;
  const int bh = blockIdx.y, b = bh >> 3, h = bh & 7;
  const int m0 = blockIdx.x * 64;
  const int lane = tid & 63, w = tid >> 6;
  const int ml = lane & 15, kl = lane >> 4;
  const int lr = lane >> 3;
  const int lc = (lane & 7) * 8;
  const u16* Ap = pb + ((size_t)bh * L_ + m0) * S_;
  const u16* Bp = vT + ((size_t)b * 512 + h * 64) * S_;

  floatx4 acc[4] = {};

  for (int k0 = 0; k0 < 2048; k0 += 64) {
    if constexpr (BF16IN) {
#pragma unroll
      for (int i = 0; i < 2; ++i) {
        const int c = w * 2 + i;     // chunk 0..7 -> rows c*8..c*8+7
        const int r = c * 8 + lr;
        gload16(&Ap[(size_t)r * S_ + k0 + lc], &As[c * 8][0]);
        gload16(&Bp[(size_t)r * S_ + k0 + lc], &Bs[c * 8][0]);
      }
    } else {
      const int srow = tid >> 4, scg = tid & 15;
#pragma unroll
      for (int i = 0; i < 4; ++i) {
        const int r = srow + i * 16;
        float4 av = *(const float4*)&probsf[((size_t)bh * L_ + m0 + r) * S_ + k0 + scg * 4];
        ushort4 ua; ua.x = f2bf(av.x); ua.y = f2bf(av.y); ua.z = f2bf(av.z); ua.w = f2bf(av.w);
        *(ushort4*)&As[r][scg * 4] = ua;
      }
#pragma unroll
      for (int i = 0; i < 2; ++i) {
        const int c = w * 2 + i;
        const int r = c * 8 + lr;
        gload16(&Bp[(size_t)r * S_ + k0 + lc], &Bs[c * 8][0]);
      }
    }
    __syncthreads();
#pragma unroll
    for (int kk = 0; kk < 64; kk += 32) {
      bf16x8 af = *(const bf16x8*)&As[w * 16 + ml][kk + kl * 8];
#pragma unroll
      for (int j = 0; j < 4; ++j) {
        bf16x8 bfv = *(const bf16x8*)&Bs[j * 16 + ml][kk + kl * 8];
        acc[j] = __builtin_amdgcn_mfma_f32_16x16x32_bf16(af, bfv, acc[j], 0, 0, 0);
      }
    }
    __syncthreads();
  }
#pragma unroll
  for (int j = 0; j < 4; ++j) {
    const int gc = h * 64 + j * 16 + ml;
#pragma unroll
    for (int r = 0; r < 4; ++r) {
      const int gl = m0 + w * 16 + kl * 4 + r;
      ctx[((size_t)b * L_ + gl) * 512 + gc] = acc[j][r];
    }
  }
}

// ---------------------------------------------------------------------------
extern "C" void kernel_launch(void* const* d_in, const int* in_sizes, int n_in,
                              void* d_out, int out_size, void* d_ws, size_t ws_size,
                              hipStream_t stream) {
  const float* queries = (const float*)d_in[0];
  const float* keys    = (const float*)d_in[1];
  const float* values  = (const float*)d_in[2];
  const float* Wq  = (const float*)d_in[4];
  const float* Wk  = (const float*)d_in[5];
  const float* Wv  = (const float*)d_in[6];
  const float* bv  = (const float*)d_in[7];
  const float* Wcb = (const float*)d_in[8];
  const float* mixing = (const float*)d_in[9];
  const float* Wd  = (const float*)d_in[10];
  const float* bd  = (const float*)d_in[11];

  float* out   = (float*)d_out;                         // [B,L,512] fp32
  float* probs = out + (size_t)B_ * L_ * 512;           // [B,H,L,S] fp32

  char* ws = (char*)d_ws;
  u16*   qb  = (u16*)(ws);                              //  4 MB  bf16 [B*L,512]
  u16*   kb  = (u16*)(ws + (size_t)4  * 1024 * 1024);   //  4 MB  bf16 [B*S,512]
  u16*   vb  = (u16*)(ws + (size_t)8  * 1024 * 1024);   //  4 MB  bf16 [B*S,512]
  u16*   vT  = (u16*)(ws + (size_t)12 * 1024 * 1024);   //  4 MB  bf16 [B,512,S]
  float* cbuf= (float*)(ws + (size_t)16 * 1024 * 1024); // 128 KB fp32 [B,H,S]
  float* ctx = (float*)(ws + (size_t)17 * 1024 * 1024); //  8 MB  fp32 [B*L,512]
  u16*   mq  = (u16*)(ws + (size_t)25 * 1024 * 1024);   // 32 MB  bf16 [B,H,L,512]
  // bf16 scores/probs buffer (128 MiB) after mq, if the workspace allows
  const size_t SB16_OFF = (size_t)57 * 1024 * 1024;
  const size_t SB16_SZ  = (size_t)B_ * H_ * L_ * S_ * 2;
  u16* sb16 = (u16*)(ws + SB16_OFF);
  const bool bigws = (ws_size >= SB16_OFF + SB16_SZ);

  hipLaunchKernelGGL(qkv_gemm, dim3(4, 32, 3), dim3(256), 0, stream,
                     queries, keys, values, Wq, Wk, Wv, bv, qb, kb, vb);
  hipLaunchKernelGGL(mixq_kernel, dim3(1024), dim3(256), 0, stream, qb, mixing, mq);
  hipLaunchKernelGGL(cb_kernel, dim3(1024), dim3(256), 0, stream, keys, Wcb, cbuf);
  hipLaunchKernelGGL(transpose_v, dim3(8, 32, 2), dim3(256), 0, stream, vb, vT);
  if (bigws) {
    hipLaunchKernelGGL(HIP_KERNEL_NAME(scores_gemm<1>), dim3(16, 16, 16), dim3(256), 0, stream,
                       mq, kb, cbuf, probs, sb16);
    hipLaunchKernelGGL(HIP_KERNEL_NAME(softmax_stream<1>), dim3(8192), dim3(256), 0, stream,
                       sb16, probs);
    hipLaunchKernelGGL(HIP_KERNEL_NAME(ctx_gemm<1>), dim3(32, 16), dim3(256), 0, stream,
                       probs, sb16, vT, ctx);
  } else {
    hipLaunchKernelGGL(HIP_KERNEL_NAME(scores_gemm<0>), dim3(16, 16, 16), dim3(256), 0, stream,
                       mq, kb, cbuf, probs, sb16);
    hipLaunchKernelGGL(HIP_KERNEL_NAME(softmax_stream<0>), dim3(8192), dim3(256), 0, stream,
                       sb16, probs);
    hipLaunchKernelGGL(HIP_KERNEL_NAME(ctx_gemm<0>), dim3(32, 16), dim3(256), 0, stream,
                       probs, sb16, vT, ctx);
  }
  hipLaunchKernelGGL(out_gemm, dim3(4, 32, 1), dim3(256), 0, stream,
                     ctx, Wd, bd, out);
}

// Round 3
// 563.526 us; speedup vs baseline: 1.2001x; 1.0285x over previous
//
#include <hip/hip_runtime.h>

typedef unsigned short u16;
typedef __bf16 bf16x8 __attribute__((ext_vector_type(8)));
typedef float floatx4 __attribute__((ext_vector_type(4)));

#define B_ 2
#define L_ 2048
#define S_ 2048
#define D_ 512
#define H_ 8

static __device__ __forceinline__ u16 f2bf(float f) {
  union { float f; unsigned u; } v; v.f = f;
  unsigned u = v.u;
  return (u16)((u + 0x7FFFu + ((u >> 16) & 1u)) >> 16);  // RNE
}
static __device__ __forceinline__ float bf2f(u16 h) {
  union { unsigned u; float f; } v; v.u = ((unsigned)h) << 16;
  return v.f;
}

// async global->LDS, 16B per lane. LDS dest is wave-uniform base + lane*16.
static __device__ __forceinline__ void gload16(const void* g, void* l) {
  __builtin_amdgcn_global_load_lds(
      (const __attribute__((address_space(1))) void*)g,
      (__attribute__((address_space(3))) void*)l, 16, 0, 0);
}

// ---------------------------------------------------------------------------
// QKV projection GEMM: C[m][n] = sum_k A[m][k] * W[n][k]   (M=4096,N=512,K=512)
// z: 0 queries->qb (bf16), 1 keys->kb (bf16), 2 values->vb (bf16,+bv)
// ---------------------------------------------------------------------------
__global__ __launch_bounds__(256) void qkv_gemm(
    const float* __restrict__ Qin, const float* __restrict__ Kin, const float* __restrict__ Vin,
    const float* __restrict__ Wq, const float* __restrict__ Wk, const float* __restrict__ Wv,
    const float* __restrict__ bv,
    u16* __restrict__ qo, u16* __restrict__ ko, u16* __restrict__ vo)
{
  __shared__ u16 As[128][72];
  __shared__ u16 Bs[128][72];
  const int z = blockIdx.z;
  const float* A = (z == 0) ? Qin : (z == 1) ? Kin : Vin;
  const float* W = (z == 0) ? Wq : (z == 1) ? Wk : Wv;
  const int tid = threadIdx.x;
  const int m0 = blockIdx.y * 128;
  const int n0 = blockIdx.x * 128;
  const int lane = tid & 63, w = tid >> 6;
  const int ml = lane & 15, kl = lane >> 4;
  const int mqw = (w >> 1) * 64, nq = (w & 1) * 64;
  const int srow = tid >> 4, scg = tid & 15;

  floatx4 acc[4][4] = {};

  for (int k0 = 0; k0 < 512; k0 += 64) {
#pragma unroll
    for (int i = 0; i < 8; ++i) {
      const int r = srow + i * 16;
      float4 av = *(const float4*)&A[(size_t)(m0 + r) * 512 + k0 + scg * 4];
      ushort4 ua; ua.x = f2bf(av.x); ua.y = f2bf(av.y); ua.z = f2bf(av.z); ua.w = f2bf(av.w);
      *(ushort4*)&As[r][scg * 4] = ua;
      float4 wv = *(const float4*)&W[(size_t)(n0 + r) * 512 + k0 + scg * 4];
      ushort4 uw; uw.x = f2bf(wv.x); uw.y = f2bf(wv.y); uw.z = f2bf(wv.z); uw.w = f2bf(wv.w);
      *(ushort4*)&Bs[r][scg * 4] = uw;
    }
    __syncthreads();
#pragma unroll
    for (int kk = 0; kk < 64; kk += 32) {
      bf16x8 af[4], bfv[4];
#pragma unroll
      for (int i = 0; i < 4; ++i) af[i] = *(const bf16x8*)&As[mqw + i * 16 + ml][kk + kl * 8];
#pragma unroll
      for (int j = 0; j < 4; ++j) bfv[j] = *(const bf16x8*)&Bs[nq + j * 16 + ml][kk + kl * 8];
#pragma unroll
      for (int i = 0; i < 4; ++i)
#pragma unroll
        for (int j = 0; j < 4; ++j)
          acc[i][j] = __builtin_amdgcn_mfma_f32_16x16x32_bf16(af[i], bfv[j], acc[i][j], 0, 0, 0);
    }
    __syncthreads();
  }
#pragma unroll
  for (int i = 0; i < 4; ++i)
#pragma unroll
    for (int j = 0; j < 4; ++j) {
      const int gc = n0 + nq + j * 16 + ml;
#pragma unroll
      for (int r = 0; r < 4; ++r) {
        const int gr = m0 + mqw + i * 16 + kl * 4 + r;
        float v = acc[i][j][r];
        if (z == 0)      qo[(size_t)gr * 512 + gc] = f2bf(v);
        else if (z == 1) ko[(size_t)gr * 512 + gc] = f2bf(v);
        else             vo[(size_t)gr * 512 + gc] = f2bf(v + bv[gc]);
      }
    }
}

// ---------------------------------------------------------------------------
// mixed_q: mq[b][h][l][e] = bf16( qb[b][l][e] * mixing[h][e] )
// ---------------------------------------------------------------------------
__global__ __launch_bounds__(256) void mixq_kernel(
    const u16* __restrict__ qb, const float* __restrict__ mixing, u16* __restrict__ mq)
{
  __shared__ float mixs[8 * 512];
  const int tid = threadIdx.x;
#pragma unroll
  for (int i = 0; i < 4; ++i)
    *(float4*)&mixs[(tid + i * 256) * 4] = *(const float4*)&mixing[(tid + i * 256) * 4];
  __syncthreads();
  const size_t unit = (size_t)blockIdx.x * 256 + tid;  // one 8-elem group
  const size_t el = unit * 8;
  const int e = (int)(el & 511);
  const size_t bl = el >> 9;
  const int b = (int)(bl >> 11);
  const int l = (int)(bl & 2047);
  uint4 qv = *(const uint4*)&qb[el];
  const float q0 = bf2f((u16)(qv.x & 0xFFFFu)), q1 = bf2f((u16)(qv.x >> 16));
  const float q2 = bf2f((u16)(qv.y & 0xFFFFu)), q3 = bf2f((u16)(qv.y >> 16));
  const float q4 = bf2f((u16)(qv.z & 0xFFFFu)), q5 = bf2f((u16)(qv.z >> 16));
  const float q6 = bf2f((u16)(qv.w & 0xFFFFu)), q7 = bf2f((u16)(qv.w >> 16));
#pragma unroll
  for (int h = 0; h < 8; ++h) {
    const float* mp = &mixs[h * 512 + e];
    uint4 o;
    o.x = (unsigned)f2bf(q0 * mp[0]) | ((unsigned)f2bf(q1 * mp[1]) << 16);
    o.y = (unsigned)f2bf(q2 * mp[2]) | ((unsigned)f2bf(q3 * mp[3]) << 16);
    o.z = (unsigned)f2bf(q4 * mp[4]) | ((unsigned)f2bf(q5 * mp[5]) << 16);
    o.w = (unsigned)f2bf(q6 * mp[6]) | ((unsigned)f2bf(q7 * mp[7]) << 16);
    *(uint4*)&mq[(((size_t)b * 8 + h) * 2048 + l) * 512 + e] = o;
  }
}

// ---------------------------------------------------------------------------
// Output projection GEMM: out[m][n] = sum_k (ctx0+ctx1)[m][k]*Wd[n][k] + bd[n]
// (split-K ctx partials summed for free during fp32 A-staging)
// ---------------------------------------------------------------------------
__global__ __launch_bounds__(256) void out_gemm(
    const float* __restrict__ A0, const float* __restrict__ A1,
    const float* __restrict__ W,
    const float* __restrict__ bias, float* __restrict__ out)
{
  __shared__ u16 As[128][72];
  __shared__ u16 Bs[128][72];
  const int tid = threadIdx.x;
  const int m0 = blockIdx.y * 128;
  const int n0 = blockIdx.x * 128;
  const int lane = tid & 63, w = tid >> 6;
  const int ml = lane & 15, kl = lane >> 4;
  const int mqw = (w >> 1) * 64, nq = (w & 1) * 64;
  const int srow = tid >> 4, scg = tid & 15;

  floatx4 acc[4][4] = {};

  for (int k0 = 0; k0 < 512; k0 += 64) {
#pragma unroll
    for (int i = 0; i < 8; ++i) {
      const int r = srow + i * 16;
      const size_t aoff = (size_t)(m0 + r) * 512 + k0 + scg * 4;
      float4 a0 = *(const float4*)&A0[aoff];
      float4 a1 = *(const float4*)&A1[aoff];
      ushort4 ua;
      ua.x = f2bf(a0.x + a1.x); ua.y = f2bf(a0.y + a1.y);
      ua.z = f2bf(a0.z + a1.z); ua.w = f2bf(a0.w + a1.w);
      *(ushort4*)&As[r][scg * 4] = ua;
      float4 wv = *(const float4*)&W[(size_t)(n0 + r) * 512 + k0 + scg * 4];
      ushort4 uw; uw.x = f2bf(wv.x); uw.y = f2bf(wv.y); uw.z = f2bf(wv.z); uw.w = f2bf(wv.w);
      *(ushort4*)&Bs[r][scg * 4] = uw;
    }
    __syncthreads();
#pragma unroll
    for (int kk = 0; kk < 64; kk += 32) {
      bf16x8 af[4], bfv[4];
#pragma unroll
      for (int i = 0; i < 4; ++i) af[i] = *(const bf16x8*)&As[mqw + i * 16 + ml][kk + kl * 8];
#pragma unroll
      for (int j = 0; j < 4; ++j) bfv[j] = *(const bf16x8*)&Bs[nq + j * 16 + ml][kk + kl * 8];
#pragma unroll
      for (int i = 0; i < 4; ++i)
#pragma unroll
        for (int j = 0; j < 4; ++j)
          acc[i][j] = __builtin_amdgcn_mfma_f32_16x16x32_bf16(af[i], bfv[j], acc[i][j], 0, 0, 0);
    }
    __syncthreads();
  }
#pragma unroll
  for (int i = 0; i < 4; ++i)
#pragma unroll
    for (int j = 0; j < 4; ++j) {
      const int gc = n0 + nq + j * 16 + ml;
#pragma unroll
      for (int r = 0; r < 4; ++r) {
        const int gr = m0 + mqw + i * 16 + kl * 4 + r;
        out[(size_t)gr * 512 + gc] = acc[i][j][r] + bias[gc];
      }
    }
}

// ---------------------------------------------------------------------------
// prep: fused cb (blocks 0..1023) + v-transpose (blocks 1024..1535)
// cb[b][h][s] = sum_d keys[b][s][d] * Wcb[h][d]
// vT[b][e][s] = vb[b][s][e]
// ---------------------------------------------------------------------------
__global__ __launch_bounds__(256) void prep_kernel(
    const float* __restrict__ keys, const float* __restrict__ Wcb, float* __restrict__ cbuf,
    const u16* __restrict__ vb, u16* __restrict__ vT)
{
  __shared__ float Wl[8 * 512];   // cb weights
  __shared__ u16 t[64][72];       // transpose tile
  const int tid = threadIdx.x;
  if (blockIdx.x < 1024) {
    // ---- content bias ----
#pragma unroll
    for (int i = 0; i < 4; ++i) {
      const int idx = tid + i * 256;
      *(float4*)&Wl[idx * 4] = *(const float4*)&Wcb[idx * 4];
    }
    __syncthreads();
    const int w = tid >> 6, lane = tid & 63;
    const int rowid = blockIdx.x * 4 + w;
    const int b = rowid >> 11, s = rowid & 2047;
    const float* kr = keys + (size_t)rowid * 512;
    float acc[8] = {0.f, 0.f, 0.f, 0.f, 0.f, 0.f, 0.f, 0.f};
    for (int e = lane; e < 512; e += 64) {
      const float kv = kr[e];
#pragma unroll
      for (int hh = 0; hh < 8; ++hh) acc[hh] += kv * Wl[hh * 512 + e];
    }
#pragma unroll
    for (int hh = 0; hh < 8; ++hh) {
#pragma unroll
      for (int off = 32; off > 0; off >>= 1) acc[hh] += __shfl_xor(acc[hh], off, 64);
    }
    if (lane == 0) {
#pragma unroll
      for (int hh = 0; hh < 8; ++hh)
        cbuf[((size_t)b * 8 + hh) * 2048 + s] = acc[hh];
    }
  } else {
    // ---- v transpose ----
    const int id = blockIdx.x - 1024;      // 0..511
    const int b = id >> 8;
    const int rem = id & 255;
    const int s0 = (rem >> 3) * 64;
    const int e0 = (rem & 7) * 64;
    const int rr = tid >> 3, g = tid & 7;
#pragma unroll
    for (int i = 0; i < 2; ++i) {
      const int r = rr + i * 32;
      *(uint4*)&t[r][g * 8] = *(const uint4*)&vb[((size_t)b * S_ + s0 + r) * 512 + e0 + g * 8];
    }
    __syncthreads();
#pragma unroll
    for (int i = 0; i < 2; ++i) {
      const int er = rr + i * 32;
      uint4 o;
      o.x = (unsigned)t[g * 8 + 0][er] | ((unsigned)t[g * 8 + 1][er] << 16);
      o.y = (unsigned)t[g * 8 + 2][er] | ((unsigned)t[g * 8 + 3][er] << 16);
      o.z = (unsigned)t[g * 8 + 4][er] | ((unsigned)t[g * 8 + 5][er] << 16);
      o.w = (unsigned)t[g * 8 + 6][er] | ((unsigned)t[g * 8 + 7][er] << 16);
      *(uint4*)&vT[((size_t)b * 512 + e0 + er) * S_ + s0 + g * 8] = o;
    }
  }
}

// ---------------------------------------------------------------------------
// Scores GEMM (per b,h): sc[l][s] = (sum_e mq[bh][l][e]*k[s][e] + cb[s]) / 8
// Staging via global_load_lds width-16 into LINEAR (unpadded) LDS (m97).
// BF16OUT=1: bf16 scores to sb. BF16OUT=0: fp32 scores into probs region.
// ---------------------------------------------------------------------------
template<int BF16OUT>
__global__ __launch_bounds__(256) void scores_gemm(
    const u16* __restrict__ mq, const u16* __restrict__ kb,
    const float* __restrict__ cbuf, float* __restrict__ sc, u16* __restrict__ sb)
{
  __shared__ u16 As[128][64];   // linear: row stride 128B (global_load_lds dest)
  __shared__ u16 Bs[128][64];
  const int tid = threadIdx.x;
  const int bh = blockIdx.z, b = bh >> 3;
  const int m0 = blockIdx.y * 128;
  const int n0 = blockIdx.x * 128;
  const u16* mqb = mq + (size_t)bh * L_ * 512;
  const u16* kbb = kb + (size_t)b * S_ * 512;
  const int lane = tid & 63, w = tid >> 6;
  const int ml = lane & 15, kl = lane >> 4;
  const int mqw = (w >> 1) * 64, nq = (w & 1) * 64;
  const int lr = lane >> 3;          // sub-row within 8-row chunk
  const int lc = (lane & 7) * 8;     // u16 col within 64

  floatx4 acc[4][4] = {};

  for (int k0 = 0; k0 < 512; k0 += 64) {
#pragma unroll
    for (int i = 0; i < 4; ++i) {
      const int c = w * 4 + i;       // 1KB chunk = 8 rows of 128B
      const int r = c * 8 + lr;
      gload16(&mqb[(size_t)(m0 + r) * 512 + k0 + lc], &As[c * 8][0]);
      gload16(&kbb[(size_t)(n0 + r) * 512 + k0 + lc], &Bs[c * 8][0]);
    }
    __syncthreads();
#pragma unroll
    for (int kk = 0; kk < 64; kk += 32) {
      bf16x8 af[4], bfv[4];
#pragma unroll
      for (int i = 0; i < 4; ++i) af[i] = *(const bf16x8*)&As[mqw + i * 16 + ml][kk + kl * 8];
#pragma unroll
      for (int j = 0; j < 4; ++j) bfv[j] = *(const bf16x8*)&Bs[nq + j * 16 + ml][kk + kl * 8];
#pragma unroll
      for (int i = 0; i < 4; ++i)
#pragma unroll
        for (int j = 0; j < 4; ++j)
          acc[i][j] = __builtin_amdgcn_mfma_f32_16x16x32_bf16(af[i], bfv[j], acc[i][j], 0, 0, 0);
    }
    __syncthreads();
  }
  if constexpr (BF16OUT) {
    u16* outp = sb + ((size_t)bh * L_ + m0) * S_ + n0;
#pragma unroll
    for (int j = 0; j < 4; ++j) {
      const int gcl = nq + j * 16 + ml;
      const float cbv = cbuf[(size_t)bh * S_ + n0 + gcl];
#pragma unroll
      for (int i = 0; i < 4; ++i)
#pragma unroll
        for (int r = 0; r < 4; ++r) {
          const int grl = mqw + i * 16 + kl * 4 + r;
          outp[(size_t)grl * S_ + gcl] = f2bf((acc[i][j][r] + cbv) * 0.125f);
        }
    }
  } else {
    float* outp = sc + ((size_t)bh * L_ + m0) * S_ + n0;
#pragma unroll
    for (int j = 0; j < 4; ++j) {
      const int gcl = nq + j * 16 + ml;
      const float cbv = cbuf[(size_t)bh * S_ + n0 + gcl];
#pragma unroll
      for (int i = 0; i < 4; ++i)
#pragma unroll
        for (int r = 0; r < 4; ++r) {
          const int grl = mqw + i * 16 + kl * 4 + r;
          outp[(size_t)grl * S_ + gcl] = (acc[i][j][r] + cbv) * 0.125f;
        }
    }
  }
}

// ---------------------------------------------------------------------------
// Streaming softmax: one wave per row, 32 vals/lane in VGPRs, single pass.
// BF16IN=1: read bf16 scores from sb, write fp32 probs AND a bf16 probs copy
// in-place into sb (consumed by ctx_gemm; saves the fp32 probs re-read).
// BF16IN=0: fp32 in place, no bf16 copy.
// ---------------------------------------------------------------------------
template<int BF16IN>
__global__ __launch_bounds__(256) void softmax_stream(
    u16* __restrict__ sb, float* probs)
{
  const int tid = threadIdx.x;
  const int row = blockIdx.x * 4 + (tid >> 6);   // bh*2048 + l
  const int lane = tid & 63;
  float s[32];
  if constexpr (BF16IN) {
    const u16* rp = sb + (size_t)row * 2048;
#pragma unroll
    for (int j = 0; j < 8; ++j) {
      uint2 v = *(const uint2*)&rp[lane * 4 + j * 256];
      s[4 * j + 0] = bf2f((u16)(v.x & 0xFFFFu));
      s[4 * j + 1] = bf2f((u16)(v.x >> 16));
      s[4 * j + 2] = bf2f((u16)(v.y & 0xFFFFu));
      s[4 * j + 3] = bf2f((u16)(v.y >> 16));
    }
  } else {
    const float* rp = probs + (size_t)row * 2048;
#pragma unroll
    for (int j = 0; j < 8; ++j) {
      float4 v = *(const float4*)&rp[lane * 4 + j * 256];
      s[4 * j + 0] = v.x; s[4 * j + 1] = v.y; s[4 * j + 2] = v.z; s[4 * j + 3] = v.w;
    }
  }
  float m = -3.0e38f;
#pragma unroll
  for (int i = 0; i < 32; ++i) m = fmaxf(m, s[i]);
#pragma unroll
  for (int off = 32; off > 0; off >>= 1) m = fmaxf(m, __shfl_xor(m, off, 64));
  float s0 = 0.f, s1 = 0.f, s2 = 0.f, s3 = 0.f;
#pragma unroll
  for (int i = 0; i < 32; i += 4) {
    s[i + 0] = __expf(s[i + 0] - m); s0 += s[i + 0];
    s[i + 1] = __expf(s[i + 1] - m); s1 += s[i + 1];
    s[i + 2] = __expf(s[i + 2] - m); s2 += s[i + 2];
    s[i + 3] = __expf(s[i + 3] - m); s3 += s[i + 3];
  }
  float sum = (s0 + s1) + (s2 + s3);
#pragma unroll
  for (int off = 32; off > 0; off >>= 1) sum += __shfl_xor(sum, off, 64);
  const float rl = 1.0f / sum;
  float* op = probs + (size_t)row * 2048;
  u16* bp = sb + (size_t)row * 2048;
#pragma unroll
  for (int j = 0; j < 8; ++j) {
    float4 o;
    o.x = s[4 * j + 0] * rl; o.y = s[4 * j + 1] * rl;
    o.z = s[4 * j + 2] * rl; o.w = s[4 * j + 3] * rl;
    *(float4*)&op[lane * 4 + j * 256] = o;
    if constexpr (BF16IN) {
      uint2 t;
      t.x = (unsigned)f2bf(o.x) | ((unsigned)f2bf(o.y) << 16);
      t.y = (unsigned)f2bf(o.z) | ((unsigned)f2bf(o.w) << 16);
      *(uint2*)&bp[lane * 4 + j * 256] = t;
    }
  }
}

// ---------------------------------------------------------------------------
// ctx GEMM (per b,h): ctx[l][dv] = sum_s p[l][s] * vT[dv][s]
// M=2048, N=64, K=2048. BM=64, BN=64. Split-K x2 (blockIdx.y) into two
// partial buffers (no atomics, no zero pass) -> 1024 blocks = 4/CU for TLP.
// out_gemm sums the partials during staging.
// ---------------------------------------------------------------------------
template<int BF16IN>
__global__ __launch_bounds__(256) void ctx_gemm(
    const float* __restrict__ probsf, const u16* __restrict__ pb,
    const u16* __restrict__ vT, float* __restrict__ ctx0, float* __restrict__ ctx1)
{
  __shared__ u16 As[64][64];   // linear, 8KB
  __shared__ u16 Bs[64][64];
  const int tid = threadIdx.x;
  const int kz = blockIdx.y;
  const int bh = blockIdx.z, b = bh >> 3, h = bh & 7;
  const int m0 = blockIdx.x * 64;
  const int lane = tid & 63, w = tid >> 6;
  const int ml = lane & 15, kl = lane >> 4;
  const int lr = lane >> 3;
  const int lc = (lane & 7) * 8;
  const u16* Ap = pb + ((size_t)bh * L_ + m0) * S_;
  const u16* Bp = vT + ((size_t)b * 512 + h * 64) * S_;

  floatx4 acc[4] = {};

  const int kend = kz * 1024 + 1024;
  for (int k0 = kz * 1024; k0 < kend; k0 += 64) {
    if constexpr (BF16IN) {
#pragma unroll
      for (int i = 0; i < 2; ++i) {
        const int c = w * 2 + i;     // chunk 0..7 -> rows c*8..c*8+7
        const int r = c * 8 + lr;
        gload16(&Ap[(size_t)r * S_ + k0 + lc], &As[c * 8][0]);
        gload16(&Bp[(size_t)r * S_ + k0 + lc], &Bs[c * 8][0]);
      }
    } else {
      const int srow = tid >> 4, scg = tid & 15;
#pragma unroll
      for (int i = 0; i < 4; ++i) {
        const int r = srow + i * 16;
        float4 av = *(const float4*)&probsf[((size_t)bh * L_ + m0 + r) * S_ + k0 + scg * 4];
        ushort4 ua; ua.x = f2bf(av.x); ua.y = f2bf(av.y); ua.z = f2bf(av.z); ua.w = f2bf(av.w);
        *(ushort4*)&As[r][scg * 4] = ua;
      }
#pragma unroll
      for (int i = 0; i < 2; ++i) {
        const int c = w * 2 + i;
        const int r = c * 8 + lr;
        gload16(&Bp[(size_t)r * S_ + k0 + lc], &Bs[c * 8][0]);
      }
    }
    __syncthreads();
#pragma unroll
    for (int kk = 0; kk < 64; kk += 32) {
      bf16x8 af = *(const bf16x8*)&As[w * 16 + ml][kk + kl * 8];
#pragma unroll
      for (int j = 0; j < 4; ++j) {
        bf16x8 bfv = *(const bf16x8*)&Bs[j * 16 + ml][kk + kl * 8];
        acc[j] = __builtin_amdgcn_mfma_f32_16x16x32_bf16(af, bfv, acc[j], 0, 0, 0);
      }
    }
    __syncthreads();
  }
  float* cdst = kz ? ctx1 : ctx0;
#pragma unroll
  for (int j = 0; j < 4; ++j) {
    const int gc = h * 64 + j * 16 + ml;
#pragma unroll
    for (int r = 0; r < 4; ++r) {
      const int gl = m0 + w * 16 + kl * 4 + r;
      cdst[((size_t)b * L_ + gl) * 512 + gc] = acc[j][r];
    }
  }
}

// ---------------------------------------------------------------------------
extern "C" void kernel_launch(void* const* d_in, const int* in_sizes, int n_in,
                              void* d_out, int out_size, void* d_ws, size_t ws_size,
                              hipStream_t stream) {
  const float* queries = (const float*)d_in[0];
  const float* keys    = (const float*)d_in[1];
  const float* values  = (const float*)d_in[2];
  const float* Wq  = (const float*)d_in[4];
  const float* Wk  = (const float*)d_in[5];
  const float* Wv  = (const float*)d_in[6];
  const float* bv  = (const float*)d_in[7];
  const float* Wcb = (const float*)d_in[8];
  const float* mixing = (const float*)d_in[9];
  const float* Wd  = (const float*)d_in[10];
  const float* bd  = (const float*)d_in[11];

  float* out   = (float*)d_out;                         // [B,L,512] fp32
  float* probs = out + (size_t)B_ * L_ * 512;           // [B,H,L,S] fp32

  char* ws = (char*)d_ws;
  u16*   qb  = (u16*)(ws);                              //  4 MB  bf16 [B*L,512]
  u16*   kb  = (u16*)(ws + (size_t)4  * 1024 * 1024);   //  4 MB  bf16 [B*S,512]
  u16*   vb  = (u16*)(ws + (size_t)8  * 1024 * 1024);   //  4 MB  bf16 [B*S,512]
  u16*   vT  = (u16*)(ws + (size_t)12 * 1024 * 1024);   //  4 MB  bf16 [B,512,S]
  float* cbuf= (float*)(ws + (size_t)16 * 1024 * 1024); // 128 KB fp32 [B,H,S]
  float* ctx0= (float*)(ws + (size_t)17 * 1024 * 1024); //  8 MB  fp32 [B*L,512]
  u16*   mq  = (u16*)(ws + (size_t)25 * 1024 * 1024);   // 32 MB  bf16 [B,H,L,512]
  // bf16 scores/probs buffer (128 MiB) after mq, if the workspace allows
  const size_t SB16_OFF = (size_t)57 * 1024 * 1024;
  const size_t SB16_SZ  = (size_t)B_ * H_ * L_ * S_ * 2;
  u16* sb16 = (u16*)(ws + SB16_OFF);
  const bool bigws = (ws_size >= SB16_OFF + SB16_SZ + (size_t)8 * 1024 * 1024);
  // second ctx partial: after sb16 when bigws, else in the (unused) sb16 slot
  float* ctx1 = bigws ? (float*)(ws + SB16_OFF + SB16_SZ)
                      : (float*)(ws + SB16_OFF);

  hipLaunchKernelGGL(qkv_gemm, dim3(4, 32, 3), dim3(256), 0, stream,
                     queries, keys, values, Wq, Wk, Wv, bv, qb, kb, vb);
  hipLaunchKernelGGL(mixq_kernel, dim3(1024), dim3(256), 0, stream, qb, mixing, mq);
  hipLaunchKernelGGL(prep_kernel, dim3(1536), dim3(256), 0, stream,
                     keys, Wcb, cbuf, vb, vT);
  if (bigws) {
    hipLaunchKernelGGL(HIP_KERNEL_NAME(scores_gemm<1>), dim3(16, 16, 16), dim3(256), 0, stream,
                       mq, kb, cbuf, probs, sb16);
    hipLaunchKernelGGL(HIP_KERNEL_NAME(softmax_stream<1>), dim3(8192), dim3(256), 0, stream,
                       sb16, probs);
    hipLaunchKernelGGL(HIP_KERNEL_NAME(ctx_gemm<1>), dim3(32, 2, 16), dim3(256), 0, stream,
                       probs, sb16, vT, ctx0, ctx1);
  } else {
    hipLaunchKernelGGL(HIP_KERNEL_NAME(scores_gemm<0>), dim3(16, 16, 16), dim3(256), 0, stream,
                       mq, kb, cbuf, probs, sb16);
    hipLaunchKernelGGL(HIP_KERNEL_NAME(softmax_stream<0>), dim3(8192), dim3(256), 0, stream,
                       sb16, probs);
    hipLaunchKernelGGL(HIP_KERNEL_NAME(ctx_gemm<0>), dim3(32, 2, 16), dim3(256), 0, stream,
                       probs, sb16, vT, ctx0, ctx1);
  }
  hipLaunchKernelGGL(out_gemm, dim3(4, 32, 1), dim3(256), 0, stream,
                     ctx0, ctx1, Wd, bd, out);
}